// Round 11
// baseline (203.391 us; speedup 1.0000x reference)
//
#include <hip/hip_runtime.h>

typedef unsigned short u16;
typedef unsigned int   u32;
typedef __bf16 bf16x8 __attribute__((ext_vector_type(8)));
typedef float  f32x4  __attribute__((ext_vector_type(4)));

#define D_MODEL 1024
#define SEQ     2048
#define NHEAD   16
#define HD      64
// (1/sqrt(64)) * log2(e): folded into Q at the projection epilogue
#define SOFTMAX_SCL 0.18033688011112042f

__device__ __forceinline__ u16 f2bf(float f) {
    u32 u;
    __builtin_memcpy(&u, &f, 4);
    u32 r = (u + 0x7fffu + ((u >> 16) & 1u)) >> 16;
    return (u16)r;
}
__device__ __forceinline__ float bf2f(u16 v) {
    u32 u = ((u32)v) << 16;
    float f;
    __builtin_memcpy(&f, &u, 4);
    return f;
}

__device__ __forceinline__ void async_copy16(const u16* g, u16* l) {
    __builtin_amdgcn_global_load_lds(
        (__attribute__((address_space(1))) void*)g,
        (__attribute__((address_space(3))) void*)l, 16, 0, 0);
}

// pack 4 fp32 -> 4 bf16 (RNE) as uint2
__device__ __forceinline__ uint2 pack4(float a, float b, float c, float d) {
    uint2 r;
    r.x = (u32)f2bf(a) | ((u32)f2bf(b) << 16);
    r.y = (u32)f2bf(c) | ((u32)f2bf(d) << 16);
    return r;
}

// ---------------------------------------------------------------------------
// fused fp32 -> bf16 conversion for x, wq, wk, wv (one launch)
// ---------------------------------------------------------------------------
#define NX4 ((2 * SEQ * D_MODEL) / 4)     // 1,048,576
#define NW4 ((D_MODEL * D_MODEL) / 4)     //   262,144
__global__ __launch_bounds__(256) void conv_all(
    const float* __restrict__ x,  const float* __restrict__ wq,
    const float* __restrict__ wk, const float* __restrict__ wv,
    u16* __restrict__ xb, u16* __restrict__ wqb,
    u16* __restrict__ wkb, u16* __restrict__ wvb)
{
    int i = blockIdx.x * 256 + threadIdx.x;
    const float* src; u16* dst; int off;
    if (i < NX4)            { src = x;  dst = xb;  off = i; }
    else if (i < NX4 + NW4) { src = wq; dst = wqb; off = i - NX4; }
    else if (i < NX4 + 2 * NW4) { src = wk; dst = wkb; off = i - NX4 - NW4; }
    else                    { src = wv; dst = wvb; off = i - NX4 - 2 * NW4; }
    float4 a = ((const float4*)src)[off];
    ushort4 o;
    o.x = f2bf(a.x); o.y = f2bf(a.y); o.z = f2bf(a.z); o.w = f2bf(a.w);
    ((ushort4*)dst)[off] = o;
}

// ---------------------------------------------------------------------------
// QKV projection, 128x128 tile, BK=64, global_load_lds, XOR-swizzled LDS.
// 1-D XCD-pinned grid: bid = (z*8+bx) + 24*by -> bid%8 constant across by.
// Output-contiguous dim in MFMA m-direction -> 16x dwordx2 stores.
// ---------------------------------------------------------------------------
__global__ __launch_bounds__(256) void qkv_gemm(
    const u16* __restrict__ xb,
    const u16* __restrict__ wqb, const float* __restrict__ bq,
    const u16* __restrict__ wkb, const float* __restrict__ bk,
    const u16* __restrict__ wvb, const float* __restrict__ bv,
    u16* __restrict__ qb, u16* __restrict__ kb, u16* __restrict__ vt)
{
    const int bid  = blockIdx.x;
    const int pair = bid % 24;
    const int by   = bid / 24;          // token-block 0..31
    const int z    = pair >> 3;
    const int bx   = pair & 7;          // feature-block 0..7

    const u16* Ap; const u16* Bp;
    int m0, n0;
    if (z < 2) {
        Ap = (z == 1) ? wkb : wqb;  Bp = xb;
        m0 = bx * 128;              // feat (m)
        n0 = by * 128;              // token (n)
    } else {
        Ap = xb;  Bp = wvb;
        m0 = by * 128;              // token (m)
        n0 = bx * 128;              // feat (n)
    }

    __shared__ u16 As[128 * 64];
    __shared__ u16 Bs[128 * 64];

    const int tid  = threadIdx.x;
    const int wave = tid >> 6;
    const int lane = tid & 63;
    const int quad = lane >> 4;
    const int l16  = lane & 15;
    const int wm   = wave >> 1;
    const int wn   = wave & 1;
    const int swz  = l16 & 7;

    int rr[4], co[4];
#pragma unroll
    for (int t = 0; t < 4; ++t) {
        int ch = (wave * 4 + t) * 64 + lane;
        rr[t] = ch >> 3;
        co[t] = ((ch & 7) ^ (rr[t] & 7)) * 8;
    }

    f32x4 acc[4][4] = {};

    for (int kt = 0; kt < D_MODEL; kt += 64) {
        __syncthreads();
#pragma unroll
        for (int t = 0; t < 4; ++t) {
            int chbase = (wave * 4 + t) * 64;
            async_copy16(Ap + (size_t)(m0 + rr[t]) * D_MODEL + kt + co[t], As + chbase * 8);
            async_copy16(Bp + (size_t)(n0 + rr[t]) * D_MODEL + kt + co[t], Bs + chbase * 8);
        }
        __syncthreads();

#pragma unroll
        for (int kc = 0; kc < 2; ++kc) {
            bf16x8 af[4], bf_[4];
#pragma unroll
            for (int i = 0; i < 4; ++i)
                af[i] = *(const bf16x8*)&As[(wm * 64 + i * 16 + l16) * 64 + (((kc * 4 + quad) ^ swz) << 3)];
#pragma unroll
            for (int j = 0; j < 4; ++j)
                bf_[j] = *(const bf16x8*)&Bs[(wn * 64 + j * 16 + l16) * 64 + (((kc * 4 + quad) ^ swz) << 3)];
#pragma unroll
            for (int i = 0; i < 4; ++i)
#pragma unroll
                for (int j = 0; j < 4; ++j)
                    acc[i][j] = __builtin_amdgcn_mfma_f32_16x16x32_bf16(af[i], bf_[j], acc[i][j], 0, 0, 0);
        }
    }

    const int chunk_lo = (quad & 1) * 4;       // within-chunk offset (u16)
    if (z < 2) {
        u16* out = (z == 1) ? kb : qb;
        const float* bi = (z == 1) ? bk : bq;
        const float scl = (z == 1) ? 1.0f : SOFTMAX_SCL;
        const int fblk = m0 + wm * 64;         // 64-aligned feature block
#pragma unroll
        for (int i = 0; i < 4; ++i) {
            const int fb = fblk + i * 16 + quad * 4;   // 4 consecutive feats
            float4 b4 = *(const float4*)&bi[fb];
            const int chunk = i * 2 + (quad >> 1);     // (feat>>3)&7
#pragma unroll
            for (int j = 0; j < 4; ++j) {
                int token = n0 + wn * 64 + j * 16 + l16;
                uint2 pk = pack4((acc[i][j][0] + b4.x) * scl,
                                 (acc[i][j][1] + b4.y) * scl,
                                 (acc[i][j][2] + b4.z) * scl,
                                 (acc[i][j][3] + b4.w) * scl);
                size_t addr = (size_t)token * D_MODEL + fblk
                            + ((chunk ^ (token & 7)) << 3) + chunk_lo;
                *(uint2*)&out[addr] = pk;
            }
        }
    } else {
        // m = token (4 consecutive), n = feat
#pragma unroll
        for (int j = 0; j < 4; ++j) {
            int feat = n0 + wn * 64 + j * 16 + l16;
            float bias = bv[feat];
            int hh = feat >> 6, d = feat & 63;
            const size_t rowbase = ((size_t)hh * HD + d) * SEQ;
#pragma unroll
            for (int i = 0; i < 4; ++i) {
                int tok = m0 + wm * 64 + i * 16 + quad * 4;      // 4 consecutive
                int b = tok >> 11, s = tok & 2047;
                const int chunk = i * 2 + (quad >> 1);           // (s>>3)&7
                uint2 pk = pack4(acc[i][j][0] + bias, acc[i][j][1] + bias,
                                 acc[i][j][2] + bias, acc[i][j][3] + bias);
                size_t addr = (size_t)b * NHEAD * HD * SEQ + rowbase
                            + (s & ~63) + ((chunk ^ (d & 7)) << 3) + chunk_lo;
                *(uint2*)&vt[addr] = pk;
            }
        }
    }
}

// ---------------------------------------------------------------------------
// Attention (round-8 structure) with FOUR-way key split: grid 2048 blocks
// (8/CU available, LDS allows 5 resident) -> more co-resident blocks to hide
// the barrier-coupled staging chain. Each block: 128 q x 512 keys; writes
// unnormalized O (bf16) + row sums; add_ln combines 4 partials.
// ---------------------------------------------------------------------------
__global__ __launch_bounds__(256) void attn_kernel(
    const u16* __restrict__ qb, const u16* __restrict__ kb, const u16* __restrict__ vtg,
    u16* __restrict__ abp, float* __restrict__ lsums)
{
    const int bid  = blockIdx.x;
    const int bh   = bid & 31;         // (b,h): fixed XCD for all its blocks
    const int b    = bh >> 4;
    const int h    = bh & 15;
    const int q0   = ((bid >> 5) & 15) * 128;
    const int part = bid >> 9;         // key quarter 0..3

    const int tid  = threadIdx.x;
    const int wave = tid >> 6;
    const int lane = tid & 63;
    const int quad = lane >> 4;
    const int l16  = lane & 15;
    const int swz  = l16 & 7;

    __shared__ u16 Ks[4096];          // [token][chunk^(token&7)][8]
    __shared__ u16 Vt[4096];          // [d][chunk^(d&7)][8]
    __shared__ u16 Ps[8 * 1024];      // [wave][rb][r][nb][lane]

    const size_t kbase = (size_t)b * SEQ * D_MODEL + h * 64;
    const size_t vbase = (size_t)(b * NHEAD + h) * HD * SEQ;

    // Q fragments direct from swizzled global: 2 row groups x 2 k-chunks
    bf16x8 aq[2][2];
#pragma unroll
    for (int rb = 0; rb < 2; ++rb) {
        const int qrow = q0 + wave * 32 + rb * 16 + l16;
        const u16* qrp = qb + (size_t)qrow * D_MODEL + h * 64;
        aq[rb][0] = *(const bf16x8*)(qrp + ((quad ^ swz) << 3));
        aq[rb][1] = *(const bf16x8*)(qrp + (((4 + quad) ^ swz) << 3));
    }

    // staging pointers (offset into this block's 512-key quarter)
    const int r0 = tid >> 3, r1 = (tid + 256) >> 3;
    const int cs8 = (tid & 7) * 8;
    const u16* kg0 = kb + kbase + (size_t)(part * 512 + r0) * D_MODEL + cs8;
    const u16* kg1 = kb + kbase + (size_t)(part * 512 + r1) * D_MODEL + cs8;
    const u16* vg0 = vtg + vbase + (size_t)r0 * SEQ + part * 512 + cs8;
    const u16* vg1 = vtg + vbase + (size_t)r1 * SEQ + part * 512 + cs8;
    const int wofs = wave * 512;

    f32x4 oacc[2][4] = {};
    float lsum[2][4] = {};

    for (int t = 0; t < 8; ++t) {
        __syncthreads();   // previous tile fully consumed
        async_copy16(kg0, Ks + wofs);
        async_copy16(kg1, Ks + 2048 + wofs);
        async_copy16(vg0, Vt + wofs);
        async_copy16(vg1, Vt + 2048 + wofs);
        kg0 += 64 * D_MODEL; kg1 += 64 * D_MODEL;
        vg0 += 64;           vg1 += 64;
        __syncthreads();   // staging complete (vmcnt drained at barrier)

        // S = Q K^T  (Q pre-scaled: S already in log2 units)
        f32x4 sacc[2][4] = {};
#pragma unroll
        for (int c = 0; c < 2; ++c) {
            bf16x8 bk_[4];
#pragma unroll
            for (int nb = 0; nb < 4; ++nb)
                bk_[nb] = *(const bf16x8*)&Ks[(nb * 16 + l16) * 64 + (((c * 4 + quad) ^ swz) << 3)];
#pragma unroll
            for (int rb = 0; rb < 2; ++rb)
#pragma unroll
                for (int nb = 0; nb < 4; ++nb)
                    sacc[rb][nb] = __builtin_amdgcn_mfma_f32_16x16x32_bf16(aq[rb][c], bk_[nb], sacc[rb][nb], 0, 0, 0);
        }

        // p = 2^S; lane-local partial sums; P -> Ps (trunc to bf16)
#pragma unroll
        for (int rb = 0; rb < 2; ++rb)
#pragma unroll
            for (int r = 0; r < 4; ++r)
#pragma unroll
                for (int nb = 0; nb < 4; ++nb) {
                    float e = exp2f(sacc[rb][nb][r]);
                    lsum[rb][r] += e;
                    u32 bits;
                    __builtin_memcpy(&bits, &e, 4);
                    Ps[wave * 2048 + rb * 1024 + r * 256 + nb * 64 + lane] = (u16)(bits >> 16);
                }

        // O += P V   (Ps wave-private: wave-local DS ordering, no barrier)
#pragma unroll
        for (int c = 0; c < 2; ++c) {
            bf16x8 ap[2];
#pragma unroll
            for (int rb = 0; rb < 2; ++rb)
                ap[rb] = *(const bf16x8*)&Ps[wave * 2048 + rb * 1024 + (l16 & 3) * 256
                                             + (c * 2 + (quad >> 1)) * 64
                                             + (l16 >> 2) * 16 + (quad & 1) * 8];
            bf16x8 bv_[4];
#pragma unroll
            for (int nb = 0; nb < 4; ++nb)
                bv_[nb] = *(const bf16x8*)&Vt[(nb * 16 + l16) * 64 + (((c * 4 + quad) ^ swz) << 3)];
#pragma unroll
            for (int rb = 0; rb < 2; ++rb)
#pragma unroll
                for (int nb = 0; nb < 4; ++nb)
                    oacc[rb][nb] = __builtin_amdgcn_mfma_f32_16x16x32_bf16(ap[rb], bv_[nb], oacc[rb][nb], 0, 0, 0);
        }
    }

    // epilogue: row sums + UNNORMALIZED partial O (bf16) to ws
#pragma unroll
    for (int rb = 0; rb < 2; ++rb)
#pragma unroll
        for (int r = 0; r < 4; ++r) {
            float s = lsum[rb][r];
            s += __shfl_xor(s, 1, 64);
            s += __shfl_xor(s, 2, 64);
            s += __shfl_xor(s, 4, 64);
            s += __shfl_xor(s, 8, 64);
            int row = q0 + wave * 32 + rb * 16 + quad * 4 + r;
            if (l16 == 0)
                lsums[((size_t)bh * 4 + part) * SEQ + row] = s;
#pragma unroll
            for (int nb = 0; nb < 4; ++nb) {
                int d = nb * 16 + l16;
                abp[(size_t)part * SEQ * 2 * D_MODEL
                    + ((size_t)b * SEQ + row) * D_MODEL + h * 64 + d] = f2bf(oacc[rb][nb][r]);
            }
        }
}

// ---------------------------------------------------------------------------
// combine 4 key-quarters + residual add + LayerNorm, one block per row
// ---------------------------------------------------------------------------
__global__ __launch_bounds__(256) void add_ln(
    const u16* __restrict__ abp, const float* __restrict__ lsums,
    const float* __restrict__ x,
    const float* __restrict__ gamma, const float* __restrict__ beta,
    float* __restrict__ out)
{
    const int row = blockIdx.x;           // (b, s)
    const int tid = threadIdx.x;
    const size_t rb = (size_t)row * D_MODEL;
    const int b = row >> 11, s = row & 2047;
    const int h = tid >> 4;               // head of this thread's 4 columns
    const int bh = b * NHEAD + h;

    float l = 0.f;
#pragma unroll
    for (int p = 0; p < 4; ++p)
        l += lsums[((size_t)bh * 4 + p) * SEQ + s];
    float inv = 1.0f / l;

    float v[4] = {0.f, 0.f, 0.f, 0.f};
#pragma unroll
    for (int p = 0; p < 4; ++p) {
        uint2 a = ((const uint2*)(abp + (size_t)p * SEQ * 2 * D_MODEL + rb))[tid];
        v[0] += bf2f((u16)(a.x & 0xffff));
        v[1] += bf2f((u16)(a.x >> 16));
        v[2] += bf2f((u16)(a.y & 0xffff));
        v[3] += bf2f((u16)(a.y >> 16));
    }
    float4 xb = ((const float4*)(x + rb))[tid];
    v[0] = v[0] * inv + xb.x;
    v[1] = v[1] * inv + xb.y;
    v[2] = v[2] * inv + xb.z;
    v[3] = v[3] * inv + xb.w;

    float sm  = v[0] + v[1] + v[2] + v[3];
    float s2 = v[0]*v[0] + v[1]*v[1] + v[2]*v[2] + v[3]*v[3];
#pragma unroll
    for (int off = 1; off < 64; off <<= 1) {
        sm += __shfl_xor(sm, off, 64);
        s2 += __shfl_xor(s2, off, 64);
    }

    __shared__ float red[2][4];
    int wave = tid >> 6, lane = tid & 63;
    if (lane == 0) { red[0][wave] = sm; red[1][wave] = s2; }
    __syncthreads();
    float st  = red[0][0] + red[0][1] + red[0][2] + red[0][3];
    float s2t = red[1][0] + red[1][1] + red[1][2] + red[1][3];

    float mu   = st * (1.0f / D_MODEL);
    float var  = s2t * (1.0f / D_MODEL) - mu * mu;
    float rstd = rsqrtf(var + 1e-5f);

    float4 g  = ((const float4*)(gamma))[tid];
    float4 bt = ((const float4*)(beta))[tid];
    float4 o;
    o.x = (v[0] - mu) * rstd * g.x + bt.x;
    o.y = (v[1] - mu) * rstd * g.y + bt.y;
    o.z = (v[2] - mu) * rstd * g.z + bt.z;
    o.w = (v[3] - mu) * rstd * g.w + bt.w;
    ((float4*)(out + rb))[tid] = o;
}

// ---------------------------------------------------------------------------
extern "C" void kernel_launch(void* const* d_in, const int* in_sizes, int n_in,
                              void* d_out, int out_size, void* d_ws, size_t ws_size,
                              hipStream_t stream) {
    const float* x     = (const float*)d_in[0];
    const float* wq    = (const float*)d_in[1];
    const float* bq    = (const float*)d_in[2];
    const float* wk    = (const float*)d_in[3];
    const float* bk    = (const float*)d_in[4];
    const float* wv    = (const float*)d_in[5];
    const float* bv    = (const float*)d_in[6];
    const float* gamma = (const float*)d_in[7];
    const float* beta  = (const float*)d_in[8];
    float* outp = (float*)d_out;

    char* ws = (char*)d_ws;
    u16*   xb    = (u16*)(ws);                        //  8 MB
    u16*   wqb   = (u16*)(ws + ((size_t)8  << 20));   //  2 MB
    u16*   wkb   = (u16*)(ws + ((size_t)10 << 20));   //  2 MB
    u16*   wvb   = (u16*)(ws + ((size_t)12 << 20));   //  2 MB
    u16*   qb    = (u16*)(ws + ((size_t)16 << 20));   //  8 MB (swizzled)
    u16*   kb    = (u16*)(ws + ((size_t)24 << 20));   //  8 MB (swizzled)
    u16*   vt    = (u16*)(ws + ((size_t)32 << 20));   //  8 MB (transposed+swizzled)
    u16*   abp   = (u16*)(ws + ((size_t)40 << 20));   // 32 MB: 4 x bf16 partial O
    float* lsums = (float*)(ws + ((size_t)72 << 20)); //  1 MB row sums

    conv_all<<<dim3((NX4 + 3 * NW4) / 256), 256, 0, stream>>>(
        x, wq, wk, wv, xb, wqb, wkb, wvb);
    qkv_gemm<<<dim3(24 * 32), 256, 0, stream>>>(xb, wqb, bq, wkb, bk, wvb, bv, qb, kb, vt);
    attn_kernel<<<dim3(2048), 256, 0, stream>>>(qb, kb, vt, abp, lsums);
    add_ln<<<dim3(2 * SEQ), 256, 0, stream>>>(abp, lsums, x, gamma, beta, outp);
}